// Round 1
// baseline (742.520 us; speedup 1.0000x reference)
//
#include <hip/hip_runtime.h>
#include <hip/hip_bf16.h>
#include <stdint.h>

typedef __bf16 bf16x8 __attribute__((ext_vector_type(8)));
typedef float f32x4 __attribute__((ext_vector_type(4)));

// float -> bf16 round-to-nearest-even (bit trick; inputs are finite here)
__device__ inline unsigned short f2bf_rne(float f) {
  unsigned int u = __float_as_uint(f);
  u += 0x7fffu + ((u >> 16) & 1u);
  return (unsigned short)(u >> 16);
}

// w = mu + eps * exp(0.5*lv), packed to bf16. 4 elems/thread, float4 loads.
__global__ __launch_bounds__(256) void prep_weight(
    const float* __restrict__ mu, const float* __restrict__ lv,
    const float* __restrict__ eps, unsigned short* __restrict__ wbf, int n4) {
  int i = blockIdx.x * 256 + threadIdx.x;
  if (i >= n4) return;
  float4 m = ((const float4*)mu)[i];
  float4 v = ((const float4*)lv)[i];
  float4 e = ((const float4*)eps)[i];
  ushort4 p;
  p.x = f2bf_rne(m.x + e.x * __expf(0.5f * v.x));
  p.y = f2bf_rne(m.y + e.y * __expf(0.5f * v.y));
  p.z = f2bf_rne(m.z + e.z * __expf(0.5f * v.z));
  p.w = f2bf_rne(m.w + e.w * __expf(0.5f * v.w));
  ((ushort4*)wbf)[i] = p;
}

__global__ __launch_bounds__(256) void prep_x(
    const float* __restrict__ x, unsigned short* __restrict__ xbf, int n4) {
  int i = blockIdx.x * 256 + threadIdx.x;
  if (i >= n4) return;
  float4 m = ((const float4*)x)[i];
  ushort4 p;
  p.x = f2bf_rne(m.x);
  p.y = f2bf_rne(m.y);
  p.z = f2bf_rne(m.z);
  p.w = f2bf_rne(m.w);
  ((ushort4*)xbf)[i] = p;
}

// C[M,N] = A[M,K] * B[N,K]^T + bias(N), A/B bf16 row-major (K inner), C fp32.
// m97 structure: 128x128 block tile, 4 waves in 2x2, each wave 64x64 via
// 4x4 grid of 16x16x32 bf16 MFMA. BK=64. global_load_lds width=16 staging
// (LDS layout contiguous in lane order -- no padding, per the wave-uniform
// base + lane*16 deposit rule).
#define BM 128
#define BN 128
#define BK 64

__global__ __launch_bounds__(256) void gemm_bt_bias(
    const unsigned short* __restrict__ A,   // [M][K] bf16 bits
    const unsigned short* __restrict__ B,   // [N][K] bf16 bits
    const float* __restrict__ bmu, const float* __restrict__ blv,
    const float* __restrict__ beps,
    float* __restrict__ C, int M, int N, int K) {
  __shared__ __align__(16) unsigned short As[BM * BK];
  __shared__ __align__(16) unsigned short Bs[BN * BK];

  const int tid  = threadIdx.x;
  const int wave = tid >> 6;
  const int lane = tid & 63;
  const int wm = wave >> 1;   // 0..1  (M direction)
  const int wn = wave & 1;    // 0..1  (N direction)

  const int rowA0 = blockIdx.y * BM;
  const int rowB0 = blockIdx.x * BN;

  // staging: thread t loads 8 bf16 (16B); 256 threads cover 32 rows x 64 cols
  const int srow = tid >> 3;        // 0..31
  const int scol = (tid & 7) * 8;   // 0,8,..,56

  f32x4 acc[4][4];
#pragma unroll
  for (int i = 0; i < 4; ++i)
#pragma unroll
    for (int j = 0; j < 4; ++j)
      acc[i][j] = (f32x4){0.f, 0.f, 0.f, 0.f};

  const int mrow = lane & 15;        // A/B fragment row
  const int kgrp = (lane >> 4) * 8;  // fragment k-offset

  for (int k0 = 0; k0 < K; k0 += BK) {
#pragma unroll
    for (int j = 0; j < 4; ++j) {
      const int r = j * 32 + srow;
      const unsigned short* gA = A + (size_t)(rowA0 + r) * K + k0 + scol;
      const unsigned short* gB = B + (size_t)(rowB0 + r) * K + k0 + scol;
      // wave-uniform LDS base; HW deposits at base + lane*16B
      __builtin_amdgcn_global_load_lds(
          (const __attribute__((address_space(1))) unsigned int*)gA,
          (__attribute__((address_space(3))) unsigned int*)&As[(j * 256 + wave * 64) * 8],
          16, 0, 0);
      __builtin_amdgcn_global_load_lds(
          (const __attribute__((address_space(1))) unsigned int*)gB,
          (__attribute__((address_space(3))) unsigned int*)&Bs[(j * 256 + wave * 64) * 8],
          16, 0, 0);
    }
    __syncthreads();

#pragma unroll
    for (int kk = 0; kk < BK; kk += 32) {
      bf16x8 af[4], bfv[4];
#pragma unroll
      for (int mi = 0; mi < 4; ++mi)
        af[mi] = *(const bf16x8*)&As[(wm * 64 + mi * 16 + mrow) * BK + kk + kgrp];
#pragma unroll
      for (int ni = 0; ni < 4; ++ni)
        bfv[ni] = *(const bf16x8*)&Bs[(wn * 64 + ni * 16 + mrow) * BK + kk + kgrp];
#pragma unroll
      for (int mi = 0; mi < 4; ++mi)
#pragma unroll
        for (int ni = 0; ni < 4; ++ni)
          acc[mi][ni] = __builtin_amdgcn_mfma_f32_16x16x32_bf16(
              af[mi], bfv[ni], acc[mi][ni], 0, 0, 0);
    }
    __syncthreads();
  }

  // Epilogue: C/D layout col=lane&15, row=(lane>>4)*4+reg (m89-verified).
  const int colq = lane & 15;
  const int rq4  = (lane >> 4) * 4;
#pragma unroll
  for (int ni = 0; ni < 4; ++ni) {
    const int col = rowB0 + wn * 64 + ni * 16 + colq;
    const float bias = bmu[col] + beps[col] * __expf(0.5f * blv[col]);
#pragma unroll
    for (int mi = 0; mi < 4; ++mi) {
      const int rbase = rowA0 + wm * 64 + mi * 16 + rq4;
#pragma unroll
      for (int r = 0; r < 4; ++r)
        C[(size_t)(rbase + r) * N + col] = acc[mi][ni][r] + bias;
    }
  }
}

extern "C" void kernel_launch(void* const* d_in, const int* in_sizes, int n_in,
                              void* d_out, int out_size, void* d_ws, size_t ws_size,
                              hipStream_t stream) {
  const float* x    = (const float*)d_in[0];
  const float* wmu  = (const float*)d_in[1];
  const float* wlv  = (const float*)d_in[2];
  const float* bmu  = (const float*)d_in[3];
  const float* blv  = (const float*)d_in[4];
  const float* weps = (const float*)d_in[5];
  const float* beps = (const float*)d_in[6];
  float* out = (float*)d_out;

  const int M = 8192, N = 4096, K = 4096;

  // workspace: xbf [M*K] bf16 (64 MB) then wbf [N*K] bf16 (32 MB)
  unsigned short* xbf = (unsigned short*)d_ws;
  unsigned short* wbf = xbf + (size_t)M * K;

  const int n4w = N * K / 4;
  prep_weight<<<n4w / 256, 256, 0, stream>>>(wmu, wlv, weps, wbf, n4w);
  const int n4x = M * K / 4;
  prep_x<<<n4x / 256, 256, 0, stream>>>(x, xbf, n4x);

  dim3 grid(N / BN, M / BM);  // 32 x 64 = 2048 blocks
  gemm_bt_bias<<<grid, 256, 0, stream>>>(xbf, wbf, bmu, blv, beps, out, M, N, K);
}

// Round 2
// 668.853 us; speedup vs baseline: 1.1101x; 1.1101x over previous
//
#include <hip/hip_runtime.h>
#include <hip/hip_bf16.h>
#include <stdint.h>

typedef __bf16 bf16x8 __attribute__((ext_vector_type(8)));
typedef float f32x4 __attribute__((ext_vector_type(4)));
typedef unsigned short u16x8 __attribute__((ext_vector_type(8)));

// float -> bf16 round-to-nearest-even (bit trick; inputs are finite here)
__device__ inline unsigned short f2bf_rne(float f) {
  unsigned int u = __float_as_uint(f);
  u += 0x7fffu + ((u >> 16) & 1u);
  return (unsigned short)(u >> 16);
}

// w = mu + eps * exp(0.5*lv), packed bf16. 8 elems/thread, 16B store.
__global__ __launch_bounds__(256) void prep_weight(
    const float4* __restrict__ mu, const float4* __restrict__ lv,
    const float4* __restrict__ eps, u16x8* __restrict__ wbf, int n8) {
  int i = blockIdx.x * 256 + threadIdx.x;
  if (i >= n8) return;
  float4 m0 = mu[2 * i], m1 = mu[2 * i + 1];
  float4 v0 = lv[2 * i], v1 = lv[2 * i + 1];
  float4 e0 = eps[2 * i], e1 = eps[2 * i + 1];
  u16x8 p;
  p[0] = f2bf_rne(m0.x + e0.x * __expf(0.5f * v0.x));
  p[1] = f2bf_rne(m0.y + e0.y * __expf(0.5f * v0.y));
  p[2] = f2bf_rne(m0.z + e0.z * __expf(0.5f * v0.z));
  p[3] = f2bf_rne(m0.w + e0.w * __expf(0.5f * v0.w));
  p[4] = f2bf_rne(m1.x + e1.x * __expf(0.5f * v1.x));
  p[5] = f2bf_rne(m1.y + e1.y * __expf(0.5f * v1.y));
  p[6] = f2bf_rne(m1.z + e1.z * __expf(0.5f * v1.z));
  p[7] = f2bf_rne(m1.w + e1.w * __expf(0.5f * v1.w));
  wbf[i] = p;
}

__global__ __launch_bounds__(256) void prep_x(
    const float4* __restrict__ x, u16x8* __restrict__ xbf, int n8) {
  int i = blockIdx.x * 256 + threadIdx.x;
  if (i >= n8) return;
  float4 m0 = x[2 * i], m1 = x[2 * i + 1];
  u16x8 p;
  p[0] = f2bf_rne(m0.x); p[1] = f2bf_rne(m0.y);
  p[2] = f2bf_rne(m0.z); p[3] = f2bf_rne(m0.w);
  p[4] = f2bf_rne(m1.x); p[5] = f2bf_rne(m1.y);
  p[6] = f2bf_rne(m1.z); p[7] = f2bf_rne(m1.w);
  xbf[i] = p;
}

// C[M,N] = A[M,K] * B[N,K]^T + bias(N), A/B bf16 row-major (K inner), C fp32.
// 128x128 block tile, 4 waves 2x2, each wave 64x64 via 4x4 of 16x16x32 MFMA.
// LDS layout XOR-swizzled: 16B granule c of row r lives at granule c^(r&7),
// implemented on the global-address side of global_load_lds (LDS deposit is
// fixed at base + lane*16B). Fragment reads XOR back -> bank-conflict-free
// (residual 2-way aliasing is free per m136).
#define BM 128
#define BN 128
#define BK 64

__global__ __launch_bounds__(256) void gemm_bt_bias(
    const unsigned short* __restrict__ A,   // [M][K] bf16 bits
    const unsigned short* __restrict__ B,   // [N][K] bf16 bits
    const float* __restrict__ bmu, const float* __restrict__ blv,
    const float* __restrict__ beps,
    float* __restrict__ C, int M, int N, int K) {
  __shared__ __align__(16) unsigned short As[BM * BK];
  __shared__ __align__(16) unsigned short Bs[BN * BK];

  const int tid  = threadIdx.x;
  const int wave = tid >> 6;
  const int lane = tid & 63;
  const int wm = wave >> 1;   // 0..1  (M direction)
  const int wn = wave & 1;    // 0..1  (N direction)

  const int rowA0 = blockIdx.y * BM;
  const int rowB0 = blockIdx.x * BN;

  // staging: thread t loads 16B = granule cg of row srow; swizzled so that
  // LDS granule (tid&7) of row srow holds global granule (tid&7)^(srow&7)
  const int srow = tid >> 3;                                   // 0..31
  const int scol = (((tid & 7) ^ ((tid >> 3) & 7))) * 8;       // swizzled granule*8

  f32x4 acc[4][4];
#pragma unroll
  for (int i = 0; i < 4; ++i)
#pragma unroll
    for (int j = 0; j < 4; ++j)
      acc[i][j] = (f32x4){0.f, 0.f, 0.f, 0.f};

  const int mrow = lane & 15;   // fragment row (A: m, B: n)
  const int gsel = lane >> 4;   // fragment k-granule select 0..3

  for (int k0 = 0; k0 < K; k0 += BK) {
#pragma unroll
    for (int j = 0; j < 4; ++j) {
      const int r = j * 32 + srow;
      const unsigned short* gA = A + (size_t)(rowA0 + r) * K + k0 + scol;
      const unsigned short* gB = B + (size_t)(rowB0 + r) * K + k0 + scol;
      __builtin_amdgcn_global_load_lds(
          (const __attribute__((address_space(1))) unsigned int*)gA,
          (__attribute__((address_space(3))) unsigned int*)&As[(j * 256 + wave * 64) * 8],
          16, 0, 0);
      __builtin_amdgcn_global_load_lds(
          (const __attribute__((address_space(1))) unsigned int*)gB,
          (__attribute__((address_space(3))) unsigned int*)&Bs[(j * 256 + wave * 64) * 8],
          16, 0, 0);
    }
    __syncthreads();

#pragma unroll
    for (int kk = 0; kk < BK; kk += 32) {
      bf16x8 af[4], bfv[4];
#pragma unroll
      for (int mi = 0; mi < 4; ++mi) {
        const int row = wm * 64 + mi * 16 + mrow;
        const int pg = ((kk >> 3) + gsel) ^ (mrow & 7);
        af[mi] = *(const bf16x8*)&As[row * BK + pg * 8];
      }
#pragma unroll
      for (int ni = 0; ni < 4; ++ni) {
        const int row = wn * 64 + ni * 16 + mrow;
        const int pg = ((kk >> 3) + gsel) ^ (mrow & 7);
        bfv[ni] = *(const bf16x8*)&Bs[row * BK + pg * 8];
      }
#pragma unroll
      for (int mi = 0; mi < 4; ++mi)
#pragma unroll
        for (int ni = 0; ni < 4; ++ni)
          acc[mi][ni] = __builtin_amdgcn_mfma_f32_16x16x32_bf16(
              af[mi], bfv[ni], acc[mi][ni], 0, 0, 0);
    }
    __syncthreads();
  }

  // Epilogue: C/D layout col=lane&15, row=(lane>>4)*4+reg (m89-verified).
  const int colq = lane & 15;
  const int rq4  = (lane >> 4) * 4;
#pragma unroll
  for (int ni = 0; ni < 4; ++ni) {
    const int col = rowB0 + wn * 64 + ni * 16 + colq;
    const float bias = bmu[col] + beps[col] * __expf(0.5f * blv[col]);
#pragma unroll
    for (int mi = 0; mi < 4; ++mi) {
      const int rbase = rowA0 + wm * 64 + mi * 16 + rq4;
#pragma unroll
      for (int r = 0; r < 4; ++r)
        C[(size_t)(rbase + r) * N + col] = acc[mi][ni][r] + bias;
    }
  }
}

extern "C" void kernel_launch(void* const* d_in, const int* in_sizes, int n_in,
                              void* d_out, int out_size, void* d_ws, size_t ws_size,
                              hipStream_t stream) {
  const float* x    = (const float*)d_in[0];
  const float* wmu  = (const float*)d_in[1];
  const float* wlv  = (const float*)d_in[2];
  const float* bmu  = (const float*)d_in[3];
  const float* blv  = (const float*)d_in[4];
  const float* weps = (const float*)d_in[5];
  const float* beps = (const float*)d_in[6];
  float* out = (float*)d_out;

  const int M = 8192, N = 4096, K = 4096;

  // workspace: xbf [M*K] bf16 (64 MB) then wbf [N*K] bf16 (32 MB)
  unsigned short* xbf = (unsigned short*)d_ws;
  unsigned short* wbf = xbf + (size_t)M * K;

  const int n8w = N * K / 8;
  prep_weight<<<n8w / 256, 256, 0, stream>>>(
      (const float4*)wmu, (const float4*)wlv, (const float4*)weps,
      (u16x8*)wbf, n8w);
  const int n8x = M * K / 8;
  prep_x<<<n8x / 256, 256, 0, stream>>>((const float4*)x, (u16x8*)xbf, n8x);

  dim3 grid(N / BN, M / BM);  // 32 x 64 = 2048 blocks
  gemm_bt_bias<<<grid, 256, 0, stream>>>(xbf, wbf, bmu, blv, beps, out, M, N, K);
}